// Round 9
// baseline (177.763 us; speedup 1.0000x reference)
//
#include <hip/hip_runtime.h>

#define BATCH 32
#define SEQ   1024
#define DH    64

typedef short s16x4 __attribute__((ext_vector_type(4)));
typedef short s16x8 __attribute__((ext_vector_type(8)));
typedef float f32x4 __attribute__((ext_vector_type(4)));

__device__ __forceinline__ short f2bf(float f) {
    unsigned u = __float_as_uint(f);
    unsigned r = (u + 0x7FFFu + ((u >> 16) & 1u)) >> 16;   // RNE to bf16
    return (short)r;
}

__device__ __forceinline__ void gload_lds16(const void* g, void* l) {
    __builtin_amdgcn_global_load_lds(
        (const __attribute__((address_space(1))) void*)g,
        (__attribute__((address_space(3))) void*)l, 16, 0, 0);
}

// ---------------- fused prep: Qb/Wb (blocks 0..2047), Vt (blocks 2048..2559) ----------------
__global__ __launch_bounds__(256) void prep_all(
    const float4* __restrict__ Q, const float4* __restrict__ K,
    const float4* __restrict__ R, const float4* __restrict__ V,
    s16x4* __restrict__ Qb, s16x4* __restrict__ Wb, s16x4* __restrict__ Vt)
{
    __shared__ short T[64][72];                 // used by vt part only
    const int bid = blockIdx.x;
    const int t   = threadIdx.x;
    if (bid < 2048) {
        // Qb = bf16(Q*0.125), Wb = bf16(K+R)
        int i = bid * 256 + t;                  // 524288 float4 groups
        float4 q = Q[i];
        s16x4 qo;
        qo[0] = f2bf(q.x * 0.125f); qo[1] = f2bf(q.y * 0.125f);
        qo[2] = f2bf(q.z * 0.125f); qo[3] = f2bf(q.w * 0.125f);
        Qb[i] = qo;
        float4 k = K[i], r = R[i];
        s16x4 wo;
        wo[0] = f2bf(k.x + r.x); wo[1] = f2bf(k.y + r.y);
        wo[2] = f2bf(k.z + r.z); wo[3] = f2bf(k.w + r.w);
        Wb[i] = wo;
    } else {
        // Vt[b][d][m] = bf16(V[b][m][d])
        int vtb = bid - 2048;                   // 0..511
        int b = vtb >> 4, m0 = (vtb & 15) * 64;
        #pragma unroll
        for (int j = 0; j < 4; ++j) {
            int p = j * 256 + t;                // 0..1023 float4 slots
            int row = p >> 4;                   // m-local
            int c4  = p & 15;                   // d group of 4
            float4 v = V[(size_t)(b * SEQ + m0 + row) * (DH / 4) + c4];
            T[row][c4 * 4 + 0] = f2bf(v.x);
            T[row][c4 * 4 + 1] = f2bf(v.y);
            T[row][c4 * 4 + 2] = f2bf(v.z);
            T[row][c4 * 4 + 3] = f2bf(v.w);
        }
        __syncthreads();
        #pragma unroll
        for (int j = 0; j < 4; ++j) {
            int p = j * 256 + t;
            int d  = p >> 4;                    // 0..63
            int mc = p & 15;                    // m chunk of 4
            s16x4 o;
            o[0] = T[mc * 4 + 0][d];
            o[1] = T[mc * 4 + 1][d];
            o[2] = T[mc * 4 + 2][d];
            o[3] = T[mc * 4 + 3][d];
            Vt[(size_t)(b * DH + d) * (SEQ / 4) + (m0 / 4) + mc] = o;
        }
    }
}

// ---------------- main: fused S^T-compute + exp + PV, LDS-staged W/V ----------------
// R8 structure (known 177us): grid (16,32), 512 thr = 8 waves (4 rt x 2 ch),
// 8 m-iters; W/V tiles staged via global_load_lds, shared by the 4 rt-waves.
//
// Round-9 delta: barrier A (the WAR barrier between fragment reads and the
// next tile's staging) no longer uses __syncthreads(). __syncthreads implies
// s_waitcnt vmcnt(0), which drains the previous iteration's score-store acks
// through the congested write path on every wave, 8x per kernel. The required
// semantics are only "all waves' LDS reads complete": s_waitcnt lgkmcnt(0) +
// s_barrier. gload_lds writes of tile i+1 are issued only after the issuing
// wave crosses the barrier, and each wave crosses only after its reads
// completed -> safe. Barrier B stays __syncthreads (vmcnt(0) IS needed to
// publish the staged tile; it sits after ~600cy of compute so mostly covered).
__global__ __launch_bounds__(512, 4) void attn_main(
    const short* __restrict__ Qb, const short* __restrict__ Wb,
    const short* __restrict__ Vt, float* __restrict__ out,
    float* __restrict__ score)
{
    __shared__ short Wlds[2][64 * 64];          // [ch][row*64 + col] 8KB each
    __shared__ short Vlds[2][64 * 64];          // [ch][d*64 + mcol]  8KB each
    __shared__ short Ps[8][16 * 72];            // per-wave P staging (wave-private)
    __shared__ float CMo[4][64][17];            // ch1 partial O, padded stride 17
    __shared__ float CS1[4][16];                // ch1 partial row sums
    __shared__ float CINV[4][16];               // final 1/l per row
    const int tid  = threadIdx.x;
    const int wave = tid >> 6;
    const int lane = tid & 63;
    const int l15  = lane & 15;
    const int quad = lane >> 4;
    const int rt   = wave & 3;                  // row-tile within block; also wave-in-ch-group
    const int ch   = wave >> 2;                 // column half

    // Bijective XCD swizzle: each XCD owns 4 whole batches.
    const int h = blockIdx.y * 16 + blockIdx.x;        // 0..511
    const int v = (h & 7) * 64 + (h >> 3);             // bijection on 0..511
    const int b  = v >> 4;                             // 0..31
    const int n0 = (v & 15) * 64 + rt * 16;

    const short* Wbase = Wb + (size_t)b * SEQ * DH;
    const short* Vbase = Vt + (size_t)b * DH * SEQ;

    // Q B-fragments: lane -> col n0+l15, k-steps 0 and 32
    const s16x8* Qv = (const s16x8*)(Qb + (size_t)(b * SEQ + n0 + l15) * DH + quad * 8);
    s16x8 aq0 = Qv[0];
    s16x8 aq1 = Qv[4];

    // ---- staging geometry: wave rt covers rows {rt*8 + lane/8} and {+32} of
    // the 64-row tile; chunk = lane&7 (16B units); source chunk XOR-swizzled.
    const int srow = rt * 8 + (lane >> 3);             // k=0 row; k=1 adds 32
    const int sch0 = (lane & 7) ^ (srow & 7);          // swizzled source chunk
    const short* wsrc0 = Wbase + (size_t)srow        * DH + sch0 * 8;  // + m0*DH
    const short* wsrc1 = Wbase + (size_t)(srow + 32) * DH + (((lane & 7) ^ ((srow + 32) & 7)) * 8);
    const short* vsrc0 = Vbase + (size_t)srow        * SEQ + sch0 * 8; // + m0
    const short* vsrc1 = Vbase + (size_t)(srow + 32) * SEQ + (((lane & 7) ^ ((srow + 32) & 7)) * 8);
    short* wdst0 = &Wlds[ch][(rt * 8) * 64];           // wave-uniform LDS bases
    short* wdst1 = &Wlds[ch][(32 + rt * 8) * 64];
    short* vdst0 = &Vlds[ch][(rt * 8) * 64];
    short* vdst1 = &Vlds[ch][(32 + rt * 8) * 64];

    f32x4 oacc[4];
    #pragma unroll
    for (int tc = 0; tc < 4; ++tc) { oacc[tc][0] = 0.f; oacc[tc][1] = 0.f; oacc[tc][2] = 0.f; oacc[tc][3] = 0.f; }
    float lsum = 0.f;

    float* scoreRow = score + (size_t)b * SEQ * SEQ + (size_t)(n0 + l15) * SEQ;

    // ---- prologue: stage tile 0 ----
    {
        const int m0 = ch * 512;
        gload_lds16(wsrc0 + (size_t)m0 * DH, wdst0);
        gload_lds16(wsrc1 + (size_t)m0 * DH, wdst1);
        gload_lds16(vsrc0 + m0, vdst0);
        gload_lds16(vsrc1 + m0, vdst1);
    }
    __syncthreads();    // vmcnt(0): tile 0 landed; published

    for (int mi = 0; mi < 8; ++mi) {
        const int m0 = ch * 512 + mi * 64;

        // ---- fragment reads from LDS (swizzled chunks) ----
        s16x8 wv[8], vv[8];
        #pragma unroll
        for (int tc = 0; tc < 4; ++tc) {
            const int r  = tc * 16 + l15;              // W row / V d-row
            const int sw = r & 7;
            wv[tc * 2 + 0] = *(const s16x8*)&Wlds[ch][r * 64 + ((quad    ) ^ sw) * 8];
            wv[tc * 2 + 1] = *(const s16x8*)&Wlds[ch][r * 64 + ((4 + quad) ^ sw) * 8];
            vv[0 + tc]     = *(const s16x8*)&Vlds[ch][r * 64 + ((quad    ) ^ sw) * 8];
            vv[4 + tc]     = *(const s16x8*)&Vlds[ch][r * 64 + ((4 + quad) ^ sw) * 8];
        }

        // ---- barrier A: LDS-reads-complete rendezvous, NO vmcnt drain ----
        asm volatile("s_waitcnt lgkmcnt(0)" ::: "memory");
        __builtin_amdgcn_sched_barrier(0);
        __builtin_amdgcn_s_barrier();
        __builtin_amdgcn_sched_barrier(0);

        // ---- issue stage for tile mi+1; latency hides under compute below ----
        if (mi < 7) {
            const int mn = m0 + 64;
            gload_lds16(wsrc0 + (size_t)mn * DH, wdst0);
            gload_lds16(wsrc1 + (size_t)mn * DH, wdst1);
            gload_lds16(vsrc0 + mn, vdst0);
            gload_lds16(vsrc1 + mn, vdst1);
        }

        // ---- S^T tile: sacc[tc][r] = S[n0+l15][m0+tc*16+quad*4+r] ----
        f32x4 sacc[4];
        #pragma unroll
        for (int tc = 0; tc < 4; ++tc) { sacc[tc][0] = 0.f; sacc[tc][1] = 0.f; sacc[tc][2] = 0.f; sacc[tc][3] = 0.f; }
        #pragma unroll
        for (int tc = 0; tc < 4; ++tc) {
            sacc[tc] = __builtin_amdgcn_mfma_f32_16x16x32_bf16(wv[tc * 2 + 0], aq0, sacc[tc], 0, 0, 0);
            sacc[tc] = __builtin_amdgcn_mfma_f32_16x16x32_bf16(wv[tc * 2 + 1], aq1, sacc[tc], 0, 0, 0);
        }

        // ---- write raw scores: 4 consecutive m per lane -> dwordx4 ----
        #pragma unroll
        for (int tc = 0; tc < 4; ++tc)
            *(f32x4*)(scoreRow + m0 + tc * 16 + quad * 4) = sacc[tc];

        // ---- P = exp(S); per-lane partial row sum; pack 4 bf16 -> ds_write_b64 ----
        #pragma unroll
        for (int tc = 0; tc < 4; ++tc) {
            float e0 = __expf(sacc[tc][0]);
            float e1 = __expf(sacc[tc][1]);
            float e2 = __expf(sacc[tc][2]);
            float e3 = __expf(sacc[tc][3]);
            lsum += (e0 + e1) + (e2 + e3);
            s16x4 pk;
            pk[0] = f2bf(e0); pk[1] = f2bf(e1); pk[2] = f2bf(e2); pk[3] = f2bf(e3);
            *(s16x4*)&Ps[wave][l15 * 72 + tc * 16 + quad * 4] = pk;
        }

        // ---- PV: O += P @ V (wave-private LDS, in-wave lgkmcnt ordering) ----
        #pragma unroll
        for (int k0 = 0; k0 < 2; ++k0) {
            s16x8 pa = *(const s16x8*)&Ps[wave][l15 * 72 + k0 * 32 + quad * 8];
            #pragma unroll
            for (int tc = 0; tc < 4; ++tc)
                oacc[tc] = __builtin_amdgcn_mfma_f32_16x16x32_bf16(pa, vv[k0 * 4 + tc], oacc[tc], 0, 0, 0);
        }

        __syncthreads();    // barrier B: vmcnt(0) publishes tile mi+1
    }

    // ---- one-time row-sum reduce across quads (row n0+l15) ----
    lsum += __shfl_xor(lsum, 16);
    lsum += __shfl_xor(lsum, 32);

    // ---- merge column halves: plain adds (no rescale needed) ----
    if (ch == 1) {
        if (quad == 0) CS1[rt][l15] = lsum;
        #pragma unroll
        for (int tc = 0; tc < 4; ++tc)
            #pragma unroll
            for (int r = 0; r < 4; ++r)
                CMo[rt][lane][tc * 4 + r] = oacc[tc][r];
    }
    __syncthreads();
    if (ch == 0) {
        float full = lsum + CS1[rt][l15];
        if (quad == 0) CINV[rt][l15] = 1.0f / full;   // same-wave RAW: lgkmcnt-ordered
        float linv[4];
        #pragma unroll
        for (int r = 0; r < 4; ++r) linv[r] = CINV[rt][quad * 4 + r];
        #pragma unroll
        for (int tc = 0; tc < 4; ++tc)
            #pragma unroll
            for (int r = 0; r < 4; ++r) {
                float o = oacc[tc][r] + CMo[rt][lane][tc * 4 + r];
                out[(size_t)((size_t)b * SEQ + n0 + quad * 4 + r) * DH + tc * 16 + l15] = o * linv[r];
            }
    }
}

extern "C" void kernel_launch(void* const* d_in, const int* in_sizes, int n_in,
                              void* d_out, int out_size, void* d_ws, size_t ws_size,
                              hipStream_t stream) {
    const float* Q = (const float*)d_in[0];
    const float* K = (const float*)d_in[1];
    const float* V = (const float*)d_in[2];
    const float* R = (const float*)d_in[3];

    const size_t NEL = (size_t)BATCH * SEQ * DH;   // 2,097,152
    short* Qb = (short*)d_ws;
    short* Wb = Qb + NEL;
    short* Vt = Wb + NEL;

    float* out   = (float*)d_out;
    float* score = out + NEL;

    prep_all<<<dim3(2048 + 512), dim3(256), 0, stream>>>(
        (const float4*)Q, (const float4*)K, (const float4*)R, (const float4*)V,
        (s16x4*)Qb, (s16x4*)Wb, (s16x4*)Vt);
    attn_main<<<dim3(SEQ / 64, BATCH), dim3(512), 0, stream>>>(
        Qb, Wb, Vt, out, score);
}

// Round 10
// 175.909 us; speedup vs baseline: 1.0105x; 1.0105x over previous
//
#include <hip/hip_runtime.h>

#define BATCH 32
#define SEQ   1024
#define DH    64

typedef short s16x4 __attribute__((ext_vector_type(4)));
typedef short s16x8 __attribute__((ext_vector_type(8)));
typedef float f32x4 __attribute__((ext_vector_type(4)));

__device__ __forceinline__ short f2bf(float f) {
    unsigned u = __float_as_uint(f);
    unsigned r = (u + 0x7FFFu + ((u >> 16) & 1u)) >> 16;   // RNE to bf16
    return (short)r;
}

__device__ __forceinline__ void gload_lds16(const void* g, void* l) {
    __builtin_amdgcn_global_load_lds(
        (const __attribute__((address_space(1))) void*)g,
        (__attribute__((address_space(3))) void*)l, 16, 0, 0);
}

// ---------------- fused prep: Qb/Wb (blocks 0..2047), Vt (blocks 2048..2559) ----------------
__global__ __launch_bounds__(256) void prep_all(
    const float4* __restrict__ Q, const float4* __restrict__ K,
    const float4* __restrict__ R, const float4* __restrict__ V,
    s16x4* __restrict__ Qb, s16x4* __restrict__ Wb, s16x4* __restrict__ Vt)
{
    __shared__ short T[64][72];                 // used by vt part only
    const int bid = blockIdx.x;
    const int t   = threadIdx.x;
    if (bid < 2048) {
        // Qb = bf16(Q*0.125), Wb = bf16(K+R)
        int i = bid * 256 + t;                  // 524288 float4 groups
        float4 q = Q[i];
        s16x4 qo;
        qo[0] = f2bf(q.x * 0.125f); qo[1] = f2bf(q.y * 0.125f);
        qo[2] = f2bf(q.z * 0.125f); qo[3] = f2bf(q.w * 0.125f);
        Qb[i] = qo;
        float4 k = K[i], r = R[i];
        s16x4 wo;
        wo[0] = f2bf(k.x + r.x); wo[1] = f2bf(k.y + r.y);
        wo[2] = f2bf(k.z + r.z); wo[3] = f2bf(k.w + r.w);
        Wb[i] = wo;
    } else {
        // Vt[b][d][m] = bf16(V[b][m][d])
        int vtb = bid - 2048;                   // 0..511
        int b = vtb >> 4, m0 = (vtb & 15) * 64;
        #pragma unroll
        for (int j = 0; j < 4; ++j) {
            int p = j * 256 + t;                // 0..1023 float4 slots
            int row = p >> 4;                   // m-local
            int c4  = p & 15;                   // d group of 4
            float4 v = V[(size_t)(b * SEQ + m0 + row) * (DH / 4) + c4];
            T[row][c4 * 4 + 0] = f2bf(v.x);
            T[row][c4 * 4 + 1] = f2bf(v.y);
            T[row][c4 * 4 + 2] = f2bf(v.z);
            T[row][c4 * 4 + 3] = f2bf(v.w);
        }
        __syncthreads();
        #pragma unroll
        for (int j = 0; j < 4; ++j) {
            int p = j * 256 + t;
            int d  = p >> 4;                    // 0..63
            int mc = p & 15;                    // m chunk of 4
            s16x4 o;
            o[0] = T[mc * 4 + 0][d];
            o[1] = T[mc * 4 + 1][d];
            o[2] = T[mc * 4 + 2][d];
            o[3] = T[mc * 4 + 3][d];
            Vt[(size_t)(b * DH + d) * (SEQ / 4) + (m0 / 4) + mc] = o;
        }
    }
}

// ---------------- main: fused S^T-compute + exp + PV, LDS-staged W/V ----------------
// R8 structure (known 177us): grid (16,32), 512 thr = 8 waves (4 rt x 2 ch),
// 8 m-iters; W/V tiles staged via global_load_lds, shared by the 4 rt-waves.
//
// Round-10 delta: barrier B uses COUNTED vmcnt (T4 pattern, m201-verified).
// B's only requirement is "stage(mi+1)'s 4 global_load_lds ops landed". Those
// are issued BEFORE this iteration's 4 score stores, so by oldest-first vmcnt
// retirement, s_waitcnt vmcnt(4) guarantees the stage loads completed while
// letting the 4 youngest ops (the score stores) stay in flight across the
// barrier. R8/R9's __syncthreads() at B implied vmcnt(0) and drained the
// just-issued stores through the congested write path every iteration --
// the last remaining store-coupling stall. mi=7 issues no stage -> no B;
// the epilogue __syncthreads() drains everything once.
__global__ __launch_bounds__(512, 4) void attn_main(
    const short* __restrict__ Qb, const short* __restrict__ Wb,
    const short* __restrict__ Vt, float* __restrict__ out,
    float* __restrict__ score)
{
    __shared__ short Wlds[2][64 * 64];          // [ch][row*64 + col] 8KB each
    __shared__ short Vlds[2][64 * 64];          // [ch][d*64 + mcol]  8KB each
    __shared__ short Ps[8][16 * 72];            // per-wave P staging (wave-private)
    __shared__ float CMo[4][64][17];            // ch1 partial O, padded stride 17
    __shared__ float CS1[4][16];                // ch1 partial row sums
    __shared__ float CINV[4][16];               // final 1/l per row
    const int tid  = threadIdx.x;
    const int wave = tid >> 6;
    const int lane = tid & 63;
    const int l15  = lane & 15;
    const int quad = lane >> 4;
    const int rt   = wave & 3;                  // row-tile within block; also wave-in-ch-group
    const int ch   = wave >> 2;                 // column half

    // Bijective XCD swizzle: each XCD owns 4 whole batches.
    const int h = blockIdx.y * 16 + blockIdx.x;        // 0..511
    const int v = (h & 7) * 64 + (h >> 3);             // bijection on 0..511
    const int b  = v >> 4;                             // 0..31
    const int n0 = (v & 15) * 64 + rt * 16;

    const short* Wbase = Wb + (size_t)b * SEQ * DH;
    const short* Vbase = Vt + (size_t)b * DH * SEQ;

    // Q B-fragments: lane -> col n0+l15, k-steps 0 and 32
    const s16x8* Qv = (const s16x8*)(Qb + (size_t)(b * SEQ + n0 + l15) * DH + quad * 8);
    s16x8 aq0 = Qv[0];
    s16x8 aq1 = Qv[4];

    // ---- staging geometry: wave rt covers rows {rt*8 + lane/8} and {+32} of
    // the 64-row tile; chunk = lane&7 (16B units); source chunk XOR-swizzled.
    const int srow = rt * 8 + (lane >> 3);             // k=0 row; k=1 adds 32
    const int sch0 = (lane & 7) ^ (srow & 7);          // swizzled source chunk
    const short* wsrc0 = Wbase + (size_t)srow        * DH + sch0 * 8;  // + m0*DH
    const short* wsrc1 = Wbase + (size_t)(srow + 32) * DH + (((lane & 7) ^ ((srow + 32) & 7)) * 8);
    const short* vsrc0 = Vbase + (size_t)srow        * SEQ + sch0 * 8; // + m0
    const short* vsrc1 = Vbase + (size_t)(srow + 32) * SEQ + (((lane & 7) ^ ((srow + 32) & 7)) * 8);
    short* wdst0 = &Wlds[ch][(rt * 8) * 64];           // wave-uniform LDS bases
    short* wdst1 = &Wlds[ch][(32 + rt * 8) * 64];
    short* vdst0 = &Vlds[ch][(rt * 8) * 64];
    short* vdst1 = &Vlds[ch][(32 + rt * 8) * 64];

    f32x4 oacc[4];
    #pragma unroll
    for (int tc = 0; tc < 4; ++tc) { oacc[tc][0] = 0.f; oacc[tc][1] = 0.f; oacc[tc][2] = 0.f; oacc[tc][3] = 0.f; }
    float lsum = 0.f;

    float* scoreRow = score + (size_t)b * SEQ * SEQ + (size_t)(n0 + l15) * SEQ;

    // ---- prologue: stage tile 0 ----
    {
        const int m0 = ch * 512;
        gload_lds16(wsrc0 + (size_t)m0 * DH, wdst0);
        gload_lds16(wsrc1 + (size_t)m0 * DH, wdst1);
        gload_lds16(vsrc0 + m0, vdst0);
        gload_lds16(vsrc1 + m0, vdst1);
    }
    __syncthreads();    // vmcnt(0) once: tile 0 landed; published

    for (int mi = 0; mi < 8; ++mi) {
        const int m0 = ch * 512 + mi * 64;

        // ---- fragment reads from LDS (swizzled chunks) ----
        s16x8 wv[8], vv[8];
        #pragma unroll
        for (int tc = 0; tc < 4; ++tc) {
            const int r  = tc * 16 + l15;              // W row / V d-row
            const int sw = r & 7;
            wv[tc * 2 + 0] = *(const s16x8*)&Wlds[ch][r * 64 + ((quad    ) ^ sw) * 8];
            wv[tc * 2 + 1] = *(const s16x8*)&Wlds[ch][r * 64 + ((4 + quad) ^ sw) * 8];
            vv[0 + tc]     = *(const s16x8*)&Vlds[ch][r * 64 + ((quad    ) ^ sw) * 8];
            vv[4 + tc]     = *(const s16x8*)&Vlds[ch][r * 64 + ((4 + quad) ^ sw) * 8];
        }

        // ---- barrier A: LDS-reads-complete rendezvous, NO vmcnt drain ----
        asm volatile("s_waitcnt lgkmcnt(0)" ::: "memory");
        __builtin_amdgcn_sched_barrier(0);
        __builtin_amdgcn_s_barrier();
        __builtin_amdgcn_sched_barrier(0);

        // ---- issue stage for tile mi+1; latency hides under compute below ----
        if (mi < 7) {
            const int mn = m0 + 64;
            gload_lds16(wsrc0 + (size_t)mn * DH, wdst0);
            gload_lds16(wsrc1 + (size_t)mn * DH, wdst1);
            gload_lds16(vsrc0 + mn, vdst0);
            gload_lds16(vsrc1 + mn, vdst1);
        }

        // ---- S^T tile: sacc[tc][r] = S[n0+l15][m0+tc*16+quad*4+r] ----
        f32x4 sacc[4];
        #pragma unroll
        for (int tc = 0; tc < 4; ++tc) { sacc[tc][0] = 0.f; sacc[tc][1] = 0.f; sacc[tc][2] = 0.f; sacc[tc][3] = 0.f; }
        #pragma unroll
        for (int tc = 0; tc < 4; ++tc) {
            sacc[tc] = __builtin_amdgcn_mfma_f32_16x16x32_bf16(wv[tc * 2 + 0], aq0, sacc[tc], 0, 0, 0);
            sacc[tc] = __builtin_amdgcn_mfma_f32_16x16x32_bf16(wv[tc * 2 + 1], aq1, sacc[tc], 0, 0, 0);
        }

        // ---- write raw scores: 4 consecutive m per lane -> dwordx4 ----
        #pragma unroll
        for (int tc = 0; tc < 4; ++tc)
            *(f32x4*)(scoreRow + m0 + tc * 16 + quad * 4) = sacc[tc];

        // ---- P = exp(S); per-lane partial row sum; pack 4 bf16 -> ds_write_b64 ----
        #pragma unroll
        for (int tc = 0; tc < 4; ++tc) {
            float e0 = __expf(sacc[tc][0]);
            float e1 = __expf(sacc[tc][1]);
            float e2 = __expf(sacc[tc][2]);
            float e3 = __expf(sacc[tc][3]);
            lsum += (e0 + e1) + (e2 + e3);
            s16x4 pk;
            pk[0] = f2bf(e0); pk[1] = f2bf(e1); pk[2] = f2bf(e2); pk[3] = f2bf(e3);
            *(s16x4*)&Ps[wave][l15 * 72 + tc * 16 + quad * 4] = pk;
        }

        // ---- PV: O += P @ V (wave-private LDS, in-wave lgkmcnt ordering) ----
        #pragma unroll
        for (int k0 = 0; k0 < 2; ++k0) {
            s16x8 pa = *(const s16x8*)&Ps[wave][l15 * 72 + k0 * 32 + quad * 8];
            #pragma unroll
            for (int tc = 0; tc < 4; ++tc)
                oacc[tc] = __builtin_amdgcn_mfma_f32_16x16x32_bf16(pa, vv[k0 * 4 + tc], oacc[tc], 0, 0, 0);
        }

        // ---- barrier B: counted vmcnt. The 4 stage loads of tile mi+1 are
        // OLDER than this iteration's 4 score stores, so vmcnt(4) proves the
        // stage landed while the stores stay in flight across the barrier. ----
        if (mi < 7) {
            asm volatile("s_waitcnt vmcnt(4)" ::: "memory");
            __builtin_amdgcn_sched_barrier(0);
            __builtin_amdgcn_s_barrier();
            __builtin_amdgcn_sched_barrier(0);
        }
    }

    // ---- one-time row-sum reduce across quads (row n0+l15) ----
    lsum += __shfl_xor(lsum, 16);
    lsum += __shfl_xor(lsum, 32);

    // ---- merge column halves: plain adds (no rescale needed) ----
    if (ch == 1) {
        if (quad == 0) CS1[rt][l15] = lsum;
        #pragma unroll
        for (int tc = 0; tc < 4; ++tc)
            #pragma unroll
            for (int r = 0; r < 4; ++r)
                CMo[rt][lane][tc * 4 + r] = oacc[tc][r];
    }
    __syncthreads();    // full drain once (also covers outstanding stores)
    if (ch == 0) {
        float full = lsum + CS1[rt][l15];
        if (quad == 0) CINV[rt][l15] = 1.0f / full;   // same-wave RAW: lgkmcnt-ordered
        float linv[4];
        #pragma unroll
        for (int r = 0; r < 4; ++r) linv[r] = CINV[rt][quad * 4 + r];
        #pragma unroll
        for (int tc = 0; tc < 4; ++tc)
            #pragma unroll
            for (int r = 0; r < 4; ++r) {
                float o = oacc[tc][r] + CMo[rt][lane][tc * 4 + r];
                out[(size_t)((size_t)b * SEQ + n0 + quad * 4 + r) * DH + tc * 16 + l15] = o * linv[r];
            }
    }
}

extern "C" void kernel_launch(void* const* d_in, const int* in_sizes, int n_in,
                              void* d_out, int out_size, void* d_ws, size_t ws_size,
                              hipStream_t stream) {
    const float* Q = (const float*)d_in[0];
    const float* K = (const float*)d_in[1];
    const float* V = (const float*)d_in[2];
    const float* R = (const float*)d_in[3];

    const size_t NEL = (size_t)BATCH * SEQ * DH;   // 2,097,152
    short* Qb = (short*)d_ws;
    short* Wb = Qb + NEL;
    short* Vt = Wb + NEL;

    float* out   = (float*)d_out;
    float* score = out + NEL;

    prep_all<<<dim3(2048 + 512), dim3(256), 0, stream>>>(
        (const float4*)Q, (const float4*)K, (const float4*)R, (const float4*)V,
        (s16x4*)Qb, (s16x4*)Wb, (s16x4*)Vt);
    attn_main<<<dim3(SEQ / 64, BATCH), dim3(512), 0, stream>>>(
        Qb, Wb, Vt, out, score);
}